// Round 8
// baseline (6083.450 us; speedup 1.0000x reference)
//
#include <hip/hip_runtime.h>
#include <stdint.h>

typedef float f32x4 __attribute__((ext_vector_type(4)));

// Pure-f32 fused MLP, 64 rows/block, 256 threads, 4 waves.
// r8 = r4 + register-prefetch double-buffering of L1 staging (latency hiding).
// All thread mappings / L2-L4 / dist are r4-verbatim (passing, absmax 1.22e-4).
__global__ __launch_bounds__(256, 4) void mlp_kernel(
    const float* __restrict__ data,
    const float* __restrict__ W1, const float* __restrict__ b1,
    const float* __restrict__ W2, const float* __restrict__ b2,
    const float* __restrict__ W3, const float* __restrict__ b3,
    const float* __restrict__ Wout, const float* __restrict__ bout,
    float* __restrict__ proj)
{
    __shared__ __align__(16) char smem[37888];
    float* a_s  = (float*)(smem);            // L1: data tile [64][32] swizzled, 8 KB
    float* w1_s = (float*)(smem + 8192);     // L1: W1 tile [32][132], 16896 B
    float* h1s  = (float*)(smem);            // L2: [64][132], 33792 B
    float* w2s  = (float*)(smem + 33792);    // L2: W2 phase [16][64], 4 KB -> 37888
    float* h2s  = (float*)(smem);            // L3: [64][68]
    float* w3s  = (float*)(smem + 17408);    // L3: [64][32]

    const int tid = threadIdx.x;
    const size_t row0 = (size_t)blockIdx.x * 64;
    const int ty = tid & 15, tx = tid >> 4;      // compute map (r4)
    const int sr = tid >> 2, q  = tid & 3;       // A-stage map (r4)
    const int kr = tid >> 3, c8 = tid & 7;       // W-stage map (r4)

    float acc[4][8];
    #pragma unroll
    for (int r = 0; r < 4; ++r)
        #pragma unroll
        for (int c = 0; c < 8; ++c) acc[r][c] = 0.f;

    // staging registers, two sets (static names, no runtime indexing)
    f32x4 pa0, pa1, pw0, pw1, pw2, pw3;
    f32x4 qa0, qa1, qw0, qw1, qw2, qw3;

#define LOADT(IT, A0, A1, V0, V1, V2, V3) do {                                  \
    const int kb_ = (IT) * 32;                                                   \
    { const int col_ = kb_ + (q + 0) * 4;                                        \
      A0 = (col_ < 784) ? *(const f32x4*)(data + (row0 + sr)*784 + col_)         \
                        : (f32x4){0.f,0.f,0.f,0.f}; }                            \
    { const int col_ = kb_ + (q + 4) * 4;                                        \
      A1 = (col_ < 784) ? *(const f32x4*)(data + (row0 + sr)*784 + col_)         \
                        : (f32x4){0.f,0.f,0.f,0.f}; }                            \
    { const int gk_ = kb_ + kr;                                                  \
      if (gk_ < 784) {                                                           \
        const float* wp_ = W1 + (size_t)gk_*128 + c8*4;                          \
        V0 = *(const f32x4*)(wp_);      V1 = *(const f32x4*)(wp_ + 32);          \
        V2 = *(const f32x4*)(wp_ + 64); V3 = *(const f32x4*)(wp_ + 96);          \
      } else {                                                                   \
        V0 = V1 = V2 = V3 = (f32x4){0.f,0.f,0.f,0.f};                            \
      } }                                                                        \
} while (0)

#define STORET(A0, A1, V0, V1, V2, V3) do {                                     \
    *(f32x4*)(a_s + sr*32 + (((q + 0) ^ ((sr >> 2) & 7)) << 2)) = A0;            \
    *(f32x4*)(a_s + sr*32 + (((q + 4) ^ ((sr >> 2) & 7)) << 2)) = A1;            \
    float* sp_ = w1_s + kr*132 + c8*4;                                           \
    *(f32x4*)(sp_)      = V0;  *(f32x4*)(sp_ + 32) = V1;                         \
    *(f32x4*)(sp_ + 64) = V2;  *(f32x4*)(sp_ + 96) = V3;                         \
} while (0)

#define COMPUTE() do {                                                          \
    _Pragma("unroll")                                                            \
    for (int kt = 0; kt < 8; ++kt) {                                             \
        f32x4 av_[4];                                                            \
        _Pragma("unroll")                                                        \
        for (int r = 0; r < 4; ++r)                                              \
            av_[r] = *(const f32x4*)(a_s + (ty*4 + r)*32 + ((kt ^ (ty & 7)) << 2)); \
        _Pragma("unroll")                                                        \
        for (int kk = 0; kk < 4; ++kk) {                                         \
            f32x4 w0_ = *(const f32x4*)(w1_s + (kt*4 + kk)*132 + tx*8);          \
            f32x4 w1_ = *(const f32x4*)(w1_s + (kt*4 + kk)*132 + tx*8 + 4);      \
            _Pragma("unroll")                                                    \
            for (int r = 0; r < 4; ++r) {                                        \
                const float a_ = av_[r][kk];                                     \
                _Pragma("unroll")                                                \
                for (int c = 0; c < 4; ++c) {                                    \
                    acc[r][c]     += a_ * w0_[c];                                \
                    acc[r][4 + c] += a_ * w1_[c];                                \
                }                                                                \
            }                                                                    \
        }                                                                        \
    }                                                                            \
} while (0)

    // -------- L1: 25 k-tiles of 32, reg-prefetch double-buffered --------
    LOADT(0, pa0, pa1, pw0, pw1, pw2, pw3);
    #pragma unroll 1
    for (int itp = 0; itp < 12; ++itp) {
        STORET(pa0, pa1, pw0, pw1, pw2, pw3);
        __syncthreads();
        LOADT(2*itp + 1, qa0, qa1, qw0, qw1, qw2, qw3);   // prefetch under compute
        COMPUTE();
        __syncthreads();
        STORET(qa0, qa1, qw0, qw1, qw2, qw3);
        __syncthreads();
        LOADT(2*itp + 2, pa0, pa1, pw0, pw1, pw2, pw3);   // prefetch under compute
        COMPUTE();
        __syncthreads();
    }
    STORET(pa0, pa1, pw0, pw1, pw2, pw3);                 // tile 24
    __syncthreads();
    COMPUTE();
    __syncthreads();

    // epilogue: bias + relu -> h1s [64][132] (r4 verbatim)
    #pragma unroll
    for (int r = 0; r < 4; ++r) {
        const int m = ty*4 + r;
        #pragma unroll
        for (int c = 0; c < 8; ++c) {
            const int col = tx*8 + c;
            float v = acc[r][c] + b1[col];
            h1s[m*132 + col] = v > 0.f ? v : 0.f;
        }
    }

    // -------- L2: f32 VALU, 8 phases of 16 k (r4 verbatim) --------
    const int m2 = tid >> 2, nq = tid & 3;
    float h2a[16];
    #pragma unroll
    for (int i = 0; i < 16; ++i) h2a[i] = b2[nq*16 + i];
    for (int p = 0; p < 8; ++p) {
        if (p) __syncthreads();
        *(f32x4*)(w2s + tid*4) = *(const f32x4*)(W2 + p*1024 + tid*4);
        __syncthreads();
        #pragma unroll
        for (int qq = 0; qq < 4; ++qq) {
            f32x4 hq = *(const f32x4*)(h1s + m2*132 + p*16 + qq*4);
            #pragma unroll
            for (int kk = 0; kk < 4; ++kk) {
                #pragma unroll
                for (int i = 0; i < 4; ++i) {
                    f32x4 wv = *(const f32x4*)(w2s + (qq*4 + kk)*64 + nq*16 + i*4);
                    #pragma unroll
                    for (int c = 0; c < 4; ++c) h2a[i*4 + c] += hq[kk] * wv[c];
                }
            }
        }
    }
    __syncthreads();
    #pragma unroll
    for (int i = 0; i < 4; ++i) {
        f32x4 v;
        #pragma unroll
        for (int c = 0; c < 4; ++c) { float x = h2a[i*4 + c]; v[c] = x > 0.f ? x : 0.f; }
        *(f32x4*)(h2s + m2*68 + nq*16 + i*4) = v;
    }
    #pragma unroll
    for (int j = 0; j < 2; ++j) {
        int wi = j*1024 + tid*4;
        *(f32x4*)(w3s + wi) = *(const f32x4*)(W3 + wi);
    }
    __syncthreads();

    // -------- L3 + L4 (r4 verbatim) --------
    const int m3 = tid >> 2, nq3 = tid & 3;
    float h3a[8];
    #pragma unroll
    for (int i = 0; i < 8; ++i) h3a[i] = b3[nq3*8 + i];
    for (int qq = 0; qq < 16; ++qq) {
        f32x4 hq = *(const f32x4*)(h2s + m3*68 + qq*4);
        #pragma unroll
        for (int kk = 0; kk < 4; ++kk) {
            #pragma unroll
            for (int i2 = 0; i2 < 2; ++i2) {
                f32x4 wv = *(const f32x4*)(w3s + (qq*4 + kk)*32 + nq3*8 + i2*4);
                #pragma unroll
                for (int c = 0; c < 4; ++c) h3a[i2*4 + c] += hq[kk] * wv[c];
            }
        }
    }
    float p0 = 0.f, p1 = 0.f;
    #pragma unroll
    for (int i = 0; i < 8; ++i) {
        const int k = nq3*8 + i;
        float h = h3a[i] > 0.f ? h3a[i] : 0.f;
        p0 += h * Wout[k*2 + 0];
        p1 += h * Wout[k*2 + 1];
    }
    p0 += __shfl_xor(p0, 1); p0 += __shfl_xor(p0, 2);
    p1 += __shfl_xor(p1, 1); p1 += __shfl_xor(p1, 2);
    if (nq3 == 0) {
        proj[(row0 + m3)*2 + 0] = p0 + bout[0];
        proj[(row0 + m3)*2 + 1] = p1 + bout[1];
    }
#undef LOADT
#undef STORET
#undef COMPUTE
}

// gather + squared distance, f32 out (r4 verbatim)
__global__ __launch_bounds__(256) void dist_kernel(
    const float* __restrict__ proj, const int* __restrict__ idxs,
    float* __restrict__ out, int total)
{
    int gid = blockIdx.x * 256 + threadIdx.x;
    if (gid >= total) return;
    unsigned i = (unsigned)gid / 10u;
    unsigned j = (unsigned)idxs[gid];
    float dx = proj[i*2 + 0] - proj[j*2 + 0];
    float dy = proj[i*2 + 1] - proj[j*2 + 1];
    out[gid] = dx*dx + dy*dy;
}

extern "C" void kernel_launch(void* const* d_in, const int* in_sizes, int n_in,
                              void* d_out, int out_size, void* d_ws, size_t ws_size,
                              hipStream_t stream)
{
    const float* data = (const float*)d_in[0];
    const int*   idxs = (const int*)d_in[1];
    const float* W1   = (const float*)d_in[2];
    const float* b1   = (const float*)d_in[3];
    const float* W2   = (const float*)d_in[4];
    const float* b2   = (const float*)d_in[5];
    const float* W3   = (const float*)d_in[6];
    const float* b3   = (const float*)d_in[7];
    const float* Wout = (const float*)d_in[8];
    const float* bout = (const float*)d_in[9];

    const int N = in_sizes[0] / 784;           // 200000, divisible by 64
    float* proj = (float*)d_ws;                // N*2 f32 = 1,600,000 B

    mlp_kernel<<<N / 64, 256, 0, stream>>>(data, W1, b1, W2, b2, W3, b3, Wout, bout, proj);
    dist_kernel<<<(N*10 + 255) / 256, 256, 0, stream>>>(proj, idxs, (float*)d_out, N*10);
}

// Round 9
// 4658.062 us; speedup vs baseline: 1.3060x; 1.3060x over previous
//
#include <hip/hip_runtime.h>
#include <stdint.h>

typedef float f32x4 __attribute__((ext_vector_type(4)));

__device__ __forceinline__ void gll16(const float* g, float* l) {
    __builtin_amdgcn_global_load_lds(
        (const __attribute__((address_space(1))) uint32_t*)(g),
        (__attribute__((address_space(3))) uint32_t*)(l),
        16, 0, 0);   // 16B per lane, lds dst = wave-uniform base + lane*16
}

// Pure-f32 fused MLP, 64 rows/block, 256 threads, 4 waves.
// r9 = r4 compute (verbatim arithmetic) + global_load_lds double-buffered L1
// staging (A source-preswizzled so the LDS layout matches r4's exactly).
__global__ __launch_bounds__(256, 3) void mlp_kernel(
    const float* __restrict__ data,
    const float* __restrict__ W1, const float* __restrict__ b1,
    const float* __restrict__ W2, const float* __restrict__ b2,
    const float* __restrict__ W3, const float* __restrict__ b3,
    const float* __restrict__ Wout, const float* __restrict__ bout,
    float* __restrict__ proj)
{
    __shared__ __align__(16) char smem[49152];
    float* a_buf0 = (float*)(smem);            // [64][32] swz, 8 KB
    float* a_buf1 = (float*)(smem + 8192);     // 8 KB
    float* w_buf0 = (float*)(smem + 16384);    // [32][128], 16 KB
    float* w_buf1 = (float*)(smem + 32768);    // 16 KB -> 49152
    float* h1s = (float*)(smem);               // L2: [64][132], 33792 B
    float* w2s = (float*)(smem + 33792);       // L2: [16][64], 4 KB
    float* h2s = (float*)(smem);               // L3: [64][68]
    float* w3s = (float*)(smem + 17408);       // L3: [64][32]

    const int tid = threadIdx.x;
    const int wv = tid >> 6, ln = tid & 63;
    const int ty = tid & 15, tx = tid >> 4;    // compute map (r4)
    const size_t row0 = (size_t)blockIdx.x * 64;

    float acc[4][8] = {};

    // stage tile T (k = T*32..+31, T<=23 so no OOB) into (AB, WB) via DMA.
    // A layout: slot s=(row,g): content = 16B group (g ^ ((row>>2)&7))  == r4
    // W layout: [32][128] linear.
#define STAGE(T, AB, WB) do {                                                 \
    const int kb_ = (T) * 32;                                                 \
    _Pragma("unroll")                                                         \
    for (int j = 0; j < 2; ++j) {                                             \
        const int s_ = wv*128 + j*64 + ln;                                    \
        const int row_ = s_ >> 3, g_ = s_ & 7;                                \
        const int kg_ = g_ ^ ((row_ >> 2) & 7);                               \
        gll16(data + (row0 + row_)*784 + kb_ + kg_*4,                         \
              (AB) + (wv*128 + j*64)*4);                                      \
    }                                                                         \
    _Pragma("unroll")                                                         \
    for (int j = 0; j < 4; ++j) {                                             \
        const int s_ = wv*256 + j*64 + ln;                                    \
        const int k_ = s_ >> 5, c_ = s_ & 31;                                 \
        gll16(W1 + (size_t)(kb_ + k_)*128 + c_*4,                             \
              (WB) + (wv*256 + j*64)*4);                                      \
    }                                                                         \
} while (0)

#define COMPUTE32(AB, WB) do {                                                \
    _Pragma("unroll")                                                         \
    for (int kt = 0; kt < 8; ++kt) {                                          \
        f32x4 av_[4];                                                         \
        _Pragma("unroll")                                                     \
        for (int r = 0; r < 4; ++r)                                           \
            av_[r] = *(const f32x4*)((AB) + (ty*4 + r)*32 + ((kt ^ (ty & 7)) << 2)); \
        _Pragma("unroll")                                                     \
        for (int kk = 0; kk < 4; ++kk) {                                      \
            f32x4 w0_ = *(const f32x4*)((WB) + (kt*4 + kk)*128 + tx*8);       \
            f32x4 w1_ = *(const f32x4*)((WB) + (kt*4 + kk)*128 + tx*8 + 4);   \
            _Pragma("unroll")                                                 \
            for (int r = 0; r < 4; ++r) {                                     \
                const float a_ = av_[r][kk];                                  \
                _Pragma("unroll")                                             \
                for (int c = 0; c < 4; ++c) {                                 \
                    acc[r][c]     += a_ * w0_[c];                             \
                    acc[r][4 + c] += a_ * w1_[c];                             \
                }                                                             \
            }                                                                 \
        }                                                                     \
    }                                                                         \
} while (0)

    // -------- L1 main: tiles 0..23 (k 0..767), DMA double-buffered --------
    STAGE(0, a_buf0, w_buf0);
    #pragma unroll 1
    for (int itp = 0; itp < 12; ++itp) {
        __syncthreads();                       // drains buf0 stage; buf1 reads done
        STAGE(2*itp + 1, a_buf1, w_buf1);      // prefetch under compute
        COMPUTE32(a_buf0, w_buf0);
        __syncthreads();                       // drains buf1 stage; buf0 reads done
        if (itp < 11) STAGE(2*itp + 2, a_buf0, w_buf0);
        COMPUTE32(a_buf1, w_buf1);
    }
    __syncthreads();                           // all DMA drained, bufs free

    // -------- L1 tail: k 768..783, conventional staging --------
    {
        const int row_ = tid >> 2, q_ = tid & 3;
        *(f32x4*)(a_buf0 + row_*16 + q_*4) =
            *(const f32x4*)(data + (row0 + row_)*784 + 768 + q_*4);
        const int k_ = tid >> 4, c_ = tid & 15;
        *(f32x4*)(w_buf0 + k_*128 + c_*8) =
            *(const f32x4*)(W1 + (size_t)(768 + k_)*128 + c_*8);
        *(f32x4*)(w_buf0 + k_*128 + c_*8 + 4) =
            *(const f32x4*)(W1 + (size_t)(768 + k_)*128 + c_*8 + 4);
    }
    __syncthreads();
    #pragma unroll
    for (int kt = 0; kt < 4; ++kt) {
        f32x4 av_[4];
        #pragma unroll
        for (int r = 0; r < 4; ++r)
            av_[r] = *(const f32x4*)(a_buf0 + (ty*4 + r)*16 + kt*4);
        #pragma unroll
        for (int kk = 0; kk < 4; ++kk) {
            f32x4 w0_ = *(const f32x4*)(w_buf0 + (kt*4 + kk)*128 + tx*8);
            f32x4 w1_ = *(const f32x4*)(w_buf0 + (kt*4 + kk)*128 + tx*8 + 4);
            #pragma unroll
            for (int r = 0; r < 4; ++r) {
                const float a_ = av_[r][kk];
                #pragma unroll
                for (int c = 0; c < 4; ++c) {
                    acc[r][c]     += a_ * w0_[c];
                    acc[r][4 + c] += a_ * w1_[c];
                }
            }
        }
    }
    __syncthreads();                           // tail reads done before h1s overwrite

    // epilogue: bias + relu -> h1s [64][132] (r4 verbatim)
    #pragma unroll
    for (int r = 0; r < 4; ++r) {
        const int m = ty*4 + r;
        #pragma unroll
        for (int c = 0; c < 8; ++c) {
            const int col = tx*8 + c;
            float v = acc[r][c] + b1[col];
            h1s[m*132 + col] = v > 0.f ? v : 0.f;
        }
    }

    // -------- L2: f32 VALU, 8 phases of 16 k (r4 verbatim) --------
    const int m2 = tid >> 2, nq = tid & 3;
    float h2a[16];
    #pragma unroll
    for (int i = 0; i < 16; ++i) h2a[i] = b2[nq*16 + i];
    for (int p = 0; p < 8; ++p) {
        if (p) __syncthreads();
        *(f32x4*)(w2s + tid*4) = *(const f32x4*)(W2 + p*1024 + tid*4);
        __syncthreads();
        #pragma unroll
        for (int qq = 0; qq < 4; ++qq) {
            f32x4 hq = *(const f32x4*)(h1s + m2*132 + p*16 + qq*4);
            #pragma unroll
            for (int kk = 0; kk < 4; ++kk) {
                #pragma unroll
                for (int i = 0; i < 4; ++i) {
                    f32x4 wv2 = *(const f32x4*)(w2s + (qq*4 + kk)*64 + nq*16 + i*4);
                    #pragma unroll
                    for (int c = 0; c < 4; ++c) h2a[i*4 + c] += hq[kk] * wv2[c];
                }
            }
        }
    }
    __syncthreads();
    #pragma unroll
    for (int i = 0; i < 4; ++i) {
        f32x4 v;
        #pragma unroll
        for (int c = 0; c < 4; ++c) { float x = h2a[i*4 + c]; v[c] = x > 0.f ? x : 0.f; }
        *(f32x4*)(h2s + m2*68 + nq*16 + i*4) = v;
    }
    #pragma unroll
    for (int j = 0; j < 2; ++j) {
        int wi = j*1024 + tid*4;
        *(f32x4*)(w3s + wi) = *(const f32x4*)(W3 + wi);
    }
    __syncthreads();

    // -------- L3 + L4 (r4 verbatim) --------
    const int m3 = tid >> 2, nq3 = tid & 3;
    float h3a[8];
    #pragma unroll
    for (int i = 0; i < 8; ++i) h3a[i] = b3[nq3*8 + i];
    for (int qq = 0; qq < 16; ++qq) {
        f32x4 hq = *(const f32x4*)(h2s + m3*68 + qq*4);
        #pragma unroll
        for (int kk = 0; kk < 4; ++kk) {
            #pragma unroll
            for (int i2 = 0; i2 < 2; ++i2) {
                f32x4 wv3 = *(const f32x4*)(w3s + (qq*4 + kk)*32 + nq3*8 + i2*4);
                #pragma unroll
                for (int c = 0; c < 4; ++c) h3a[i2*4 + c] += hq[kk] * wv3[c];
            }
        }
    }
    float p0 = 0.f, p1 = 0.f;
    #pragma unroll
    for (int i = 0; i < 8; ++i) {
        const int k = nq3*8 + i;
        float h = h3a[i] > 0.f ? h3a[i] : 0.f;
        p0 += h * Wout[k*2 + 0];
        p1 += h * Wout[k*2 + 1];
    }
    p0 += __shfl_xor(p0, 1); p0 += __shfl_xor(p0, 2);
    p1 += __shfl_xor(p1, 1); p1 += __shfl_xor(p1, 2);
    if (nq3 == 0) {
        proj[(row0 + m3)*2 + 0] = p0 + bout[0];
        proj[(row0 + m3)*2 + 1] = p1 + bout[1];
    }
#undef STAGE
#undef COMPUTE32
}

// gather + squared distance, f32 out (r4 verbatim)
__global__ __launch_bounds__(256) void dist_kernel(
    const float* __restrict__ proj, const int* __restrict__ idxs,
    float* __restrict__ out, int total)
{
    int gid = blockIdx.x * 256 + threadIdx.x;
    if (gid >= total) return;
    unsigned i = (unsigned)gid / 10u;
    unsigned j = (unsigned)idxs[gid];
    float dx = proj[i*2 + 0] - proj[j*2 + 0];
    float dy = proj[i*2 + 1] - proj[j*2 + 1];
    out[gid] = dx*dx + dy*dy;
}

extern "C" void kernel_launch(void* const* d_in, const int* in_sizes, int n_in,
                              void* d_out, int out_size, void* d_ws, size_t ws_size,
                              hipStream_t stream)
{
    const float* data = (const float*)d_in[0];
    const int*   idxs = (const int*)d_in[1];
    const float* W1   = (const float*)d_in[2];
    const float* b1   = (const float*)d_in[3];
    const float* W2   = (const float*)d_in[4];
    const float* b2   = (const float*)d_in[5];
    const float* W3   = (const float*)d_in[6];
    const float* b3   = (const float*)d_in[7];
    const float* Wout = (const float*)d_in[8];
    const float* bout = (const float*)d_in[9];

    const int N = in_sizes[0] / 784;           // 200000, divisible by 64
    float* proj = (float*)d_ws;                // N*2 f32 = 1,600,000 B

    mlp_kernel<<<N / 64, 256, 0, stream>>>(data, W1, b1, W2, b2, W3, b3, Wout, bout, proj);
    dist_kernel<<<(N*10 + 255) / 256, 256, 0, stream>>>(proj, idxs, (float*)d_out, N*10);
}

// Round 10
// 1128.490 us; speedup vs baseline: 5.3908x; 4.1277x over previous
//
#include <hip/hip_runtime.h>
#include <stdint.h>

typedef float f32x4 __attribute__((ext_vector_type(4)));

// Pure-f32 fused MLP. 128 threads (2 waves) per block, 64 rows/block.
// 8x8 register tile in L1 (LDS-instr/FMA halved vs r4), 8x4 in L2, 4x4 in L3.
// All LDS tiles XOR-swizzled; staging writes are wave-contiguous 1KB.
__global__ __launch_bounds__(128, 2) void mlp_kernel(
    const float* __restrict__ data,
    const float* __restrict__ W1, const float* __restrict__ b1,
    const float* __restrict__ W2, const float* __restrict__ b2,
    const float* __restrict__ W3, const float* __restrict__ b3,
    const float* __restrict__ Wout, const float* __restrict__ bout,
    float* __restrict__ proj)
{
    __shared__ __align__(16) char smem[36864];
    float* a_s  = (float*)(smem);          // L1 A [64][32] swz, 8 KB
    float* w1_s = (float*)(smem + 8192);   // L1 W [32][128] swz, 16 KB -> 24576
    float* h1s  = (float*)(smem);          // L2 h1 [64][128] swz, 32 KB
    float* w2s  = (float*)(smem + 32768);  // L2 W2 phase [16][64], 4 KB -> 36864
    float* h2s  = (float*)(smem);          // L3 h2 [64][64] swz, 16 KB
    float* w3s  = (float*)(smem + 16384);  // L3 W3 [64][32], 8 KB
    float* h3s  = (float*)(smem + 24576);  // L4 h3 [64][32] swz, 8 KB -> 32768

    const int tid = threadIdx.x;
    const int ty = tid & 7;        // row group: rows ty*8 .. +7
    const int tx = tid >> 3;       // 0..15: cols tx*8 .. +7 (L1)
    const size_t row0 = (size_t)blockIdx.x * 64;

    // ---------------- Layer 1: 25 k-tiles of 32, 8x8/thread ----------------
    float acc[8][8] = {};

    #pragma unroll 1
    for (int it = 0; it < 25; ++it) {
        const int kb = it * 32;
        // A stage: 512 f32x4, 4/thread; store slot g^((row>>3)&7), content group g
        #pragma unroll
        for (int j = 0; j < 4; ++j) {
            const int s = j*128 + tid;
            const int row = s >> 3, g = s & 7;
            const int col = kb + g*4;
            f32x4 v = {};
            if (col < 784) v = *(const f32x4*)(data + (row0 + row)*784 + col);
            *(f32x4*)(a_s + row*32 + ((g ^ ((row >> 3) & 7)) << 2)) = v;
        }
        // W stage: 1024 f32x4, 8/thread; store slot gs^(kr&7), content group gs
        #pragma unroll
        for (int j = 0; j < 8; ++j) {
            const int s = j*128 + tid;
            const int kr = s >> 5, gs = s & 31;
            const int gk = kb + kr;
            f32x4 v = {};
            if (gk < 784) v = *(const f32x4*)(W1 + (size_t)gk*128 + gs*4);
            *(f32x4*)(w1_s + kr*128 + ((gs ^ (kr & 7)) << 2)) = v;
        }
        __syncthreads();
        #pragma unroll
        for (int kt = 0; kt < 8; ++kt) {
            f32x4 av[8];
            #pragma unroll
            for (int r = 0; r < 8; ++r)
                av[r] = *(const f32x4*)(a_s + (ty*8 + r)*32 + ((kt ^ ty) << 2));
            #pragma unroll
            for (int kk = 0; kk < 4; ++kk) {
                const int k = kt*4 + kk;
                f32x4 w0  = *(const f32x4*)(w1_s + k*128 + (((tx*2)     ^ (k & 7)) << 2));
                f32x4 w1v = *(const f32x4*)(w1_s + k*128 + (((tx*2 + 1) ^ (k & 7)) << 2));
                #pragma unroll
                for (int r = 0; r < 8; ++r) {
                    const float a = av[r][kk];
                    #pragma unroll
                    for (int c = 0; c < 4; ++c) {
                        acc[r][c]     += a * w0[c];
                        acc[r][4 + c] += a * w1v[c];
                    }
                }
            }
        }
        __syncthreads();
    }

    // L1 epilogue: bias + relu -> h1s [64][128] swz (slot G^ty, G = col>>2)
    {
        float bias[8];
        #pragma unroll
        for (int c = 0; c < 8; ++c) bias[c] = b1[tx*8 + c];
        #pragma unroll
        for (int r = 0; r < 8; ++r) {
            const int m = ty*8 + r;
            f32x4 v0, v1;
            #pragma unroll
            for (int c = 0; c < 4; ++c) {
                float x0 = acc[r][c] + bias[c];
                float x1 = acc[r][4 + c] + bias[4 + c];
                v0[c] = x0 > 0.f ? x0 : 0.f;
                v1[c] = x1 > 0.f ? x1 : 0.f;
            }
            *(f32x4*)(h1s + m*128 + (((tx*2)     ^ ty) << 2)) = v0;
            *(f32x4*)(h1s + m*128 + (((tx*2 + 1) ^ ty) << 2)) = v1;
        }
    }
    // stage W2 phase 0: [16][64], 2 f32x4/thread
    #pragma unroll
    for (int j = 0; j < 2; ++j) {
        const int s = j*128 + tid;
        const int wr = s >> 4, wc = s & 15;
        *(f32x4*)(w2s + wr*64 + wc*4) = *(const f32x4*)(W2 + wr*64 + wc*4);
    }
    __syncthreads();

    // ---------------- Layer 2: 64x64, K=128, 8 phases, 8x4/thread ----------------
    float acc2[8][4];
    #pragma unroll
    for (int r = 0; r < 8; ++r)
        #pragma unroll
        for (int c = 0; c < 4; ++c) acc2[r][c] = b2[tx*4 + c];

    #pragma unroll 1
    for (int p = 0; p < 8; ++p) {
        #pragma unroll
        for (int c4k = 0; c4k < 4; ++c4k) {
            f32x4 av2[8];
            #pragma unroll
            for (int r = 0; r < 8; ++r)
                av2[r] = *(const f32x4*)(h1s + (ty*8 + r)*128 + (((p*4 + c4k) ^ ty) << 2));
            #pragma unroll
            for (int kk = 0; kk < 4; ++kk) {
                f32x4 wv = *(const f32x4*)(w2s + (c4k*4 + kk)*64 + tx*4);
                #pragma unroll
                for (int r = 0; r < 8; ++r) {
                    const float a = av2[r][kk];
                    #pragma unroll
                    for (int c = 0; c < 4; ++c) acc2[r][c] += a * wv[c];
                }
            }
        }
        if (p < 7) {
            __syncthreads();
            #pragma unroll
            for (int j = 0; j < 2; ++j) {
                const int s = j*128 + tid;
                const int wr = s >> 4, wc = s & 15;
                *(f32x4*)(w2s + wr*64 + wc*4) =
                    *(const f32x4*)(W2 + ((p + 1)*16 + wr)*64 + wc*4);
            }
            __syncthreads();
        }
    }
    __syncthreads();   // all h1s reads done

    // L2 epilogue: relu -> h2s [64][64] swz (slot tx^((m>>2)&7)); stage W3 [64][32]
    #pragma unroll
    for (int r = 0; r < 8; ++r) {
        const int m = ty*8 + r;
        f32x4 v;
        #pragma unroll
        for (int c = 0; c < 4; ++c) { float x = acc2[r][c]; v[c] = x > 0.f ? x : 0.f; }
        *(f32x4*)(h2s + m*64 + ((tx ^ ((m >> 2) & 7)) << 2)) = v;
    }
    #pragma unroll
    for (int j = 0; j < 4; ++j) {
        const int s = j*128 + tid;
        const int k3 = s >> 3, c = s & 7;
        *(f32x4*)(w3s + k3*32 + c*4) = *(const f32x4*)(W3 + k3*32 + c*4);
    }
    __syncthreads();

    // ---------------- Layer 3: 64x32, K=64, 4x4/thread ----------------
    const int ty3 = tid & 15;      // rows ty3*4 .. +3
    const int tx3 = tid >> 4;      // 0..7: cols tx3*4 .. +3
    float acc3[4][4];
    #pragma unroll
    for (int r = 0; r < 4; ++r)
        #pragma unroll
        for (int c = 0; c < 4; ++c) acc3[r][c] = b3[tx3*4 + c];

    #pragma unroll
    for (int ch = 0; ch < 16; ++ch) {
        f32x4 av3[4];
        #pragma unroll
        for (int r = 0; r < 4; ++r)
            av3[r] = *(const f32x4*)(h2s + (ty3*4 + r)*64 + ((ch ^ (ty3 & 7)) << 2));
        #pragma unroll
        for (int kk = 0; kk < 4; ++kk) {
            f32x4 wv = *(const f32x4*)(w3s + (ch*4 + kk)*32 + tx3*4);
            #pragma unroll
            for (int r = 0; r < 4; ++r) {
                const float a = av3[r][kk];
                #pragma unroll
                for (int c = 0; c < 4; ++c) acc3[r][c] += a * wv[c];
            }
        }
    }
    // L3 epilogue: relu -> h3s [64][32] swz (slot tx3^(row&7))
    #pragma unroll
    for (int r = 0; r < 4; ++r) {
        const int row = ty3*4 + r;
        f32x4 v;
        #pragma unroll
        for (int c = 0; c < 4; ++c) { float x = acc3[r][c]; v[c] = x > 0.f ? x : 0.f; }
        *(f32x4*)(h3s + row*32 + ((tx3 ^ (row & 7)) << 2)) = v;
    }
    __syncthreads();

    // ---------------- Layer 4: proj = h3 @ Wout + bout ----------------
    {
        const int m4 = tid >> 1, half = tid & 1;
        float p0 = 0.f, p1 = 0.f;
        #pragma unroll
        for (int j = 0; j < 4; ++j) {
            const int g = half*4 + j;
            f32x4 h4 = *(const f32x4*)(h3s + m4*32 + ((g ^ (m4 & 7)) << 2));
            #pragma unroll
            for (int c = 0; c < 4; ++c) {
                const int k = g*4 + c;
                p0 += h4[c] * Wout[k*2 + 0];
                p1 += h4[c] * Wout[k*2 + 1];
            }
        }
        p0 += __shfl_xor(p0, 1);
        p1 += __shfl_xor(p1, 1);
        if (half == 0) {
            proj[(row0 + m4)*2 + 0] = p0 + bout[0];
            proj[(row0 + m4)*2 + 1] = p1 + bout[1];
        }
    }
}

// gather + squared distance, f32 out (r4 verbatim)
__global__ __launch_bounds__(256) void dist_kernel(
    const float* __restrict__ proj, const int* __restrict__ idxs,
    float* __restrict__ out, int total)
{
    int gid = blockIdx.x * 256 + threadIdx.x;
    if (gid >= total) return;
    unsigned i = (unsigned)gid / 10u;
    unsigned j = (unsigned)idxs[gid];
    float dx = proj[i*2 + 0] - proj[j*2 + 0];
    float dy = proj[i*2 + 1] - proj[j*2 + 1];
    out[gid] = dx*dx + dy*dy;
}

extern "C" void kernel_launch(void* const* d_in, const int* in_sizes, int n_in,
                              void* d_out, int out_size, void* d_ws, size_t ws_size,
                              hipStream_t stream)
{
    const float* data = (const float*)d_in[0];
    const int*   idxs = (const int*)d_in[1];
    const float* W1   = (const float*)d_in[2];
    const float* b1   = (const float*)d_in[3];
    const float* W2   = (const float*)d_in[4];
    const float* b2   = (const float*)d_in[5];
    const float* W3   = (const float*)d_in[6];
    const float* b3   = (const float*)d_in[7];
    const float* Wout = (const float*)d_in[8];
    const float* bout = (const float*)d_in[9];

    const int N = in_sizes[0] / 784;           // 200000, divisible by 64
    float* proj = (float*)d_ws;                // N*2 f32 = 1,600,000 B

    mlp_kernel<<<N / 64, 128, 0, stream>>>(data, W1, b1, W2, b2, W3, b3, Wout, bout, proj);
    dist_kernel<<<(N*10 + 255) / 256, 256, 0, stream>>>(proj, idxs, (float*)d_out, N*10);
}